// Round 14
// baseline (218.344 us; speedup 1.0000x reference)
//
#include <hip/hip_runtime.h>
#include <hip/hip_bf16.h>
#include <stdint.h>

#define DEVINL __device__ __forceinline__

using bf16x8 = __attribute__((ext_vector_type(8))) short;
using f32x4  = __attribute__((ext_vector_type(4))) float;

static constexpr int NPTS = 50000;
static constexpr int NPAD = 50176;         // 196 * 256
static constexpr int DIM  = 768;
static constexpr int DATT = 128;
static constexpr int NRB  = NPAD / 128;    // 392 row blocks (gate / partial)

DEVINL ushort f2b(float f) {               // RNE float->bf16 (finite inputs)
  uint32_t u = __float_as_uint(f);
  u += 0x7fffu + ((u >> 16) & 1u);
  return (ushort)(u >> 16);
}
DEVINL float b2f(ushort u) { return __uint_as_float(((uint32_t)u) << 16); }

DEVINL void gload_lds16(const void* g, void* l) {
  __builtin_amdgcn_global_load_lds((const __attribute__((address_space(1))) void*)g,
                                   (__attribute__((address_space(3))) void*)l,
                                   16, 0, 0);
}

// ---------------- K0: one-shot fp32->bf16 for x (+pad) and all weights --------
// 38400 blocks x 256 threads, 4 floats/thread. Lane-contiguous: 16B read/lane,
// 8B store/lane (the m13-verified 6.3 TB/s pattern). Region split by flat
// float4-index; x/pad boundary is exactly vector-aligned (NPTS*DIM/4).
static constexpr long NX4  = (long)NPAD * DIM / 4;   // 9,633,792
static constexpr long NXS4 = (long)NPTS * DIM / 4;   // 9,600,000 (exact)
static constexpr long NF4  = (long)DIM * DIM / 4;    // 147,456
static constexpr long NA4  = (long)DATT * DIM / 4;   // 24,576

__global__ __launch_bounds__(256)
void cvt_all4_kernel(const float* __restrict__ x, const float* __restrict__ Wf,
                     const float* __restrict__ Wa, const float* __restrict__ Wb,
                     ushort* __restrict__ xb, ushort* __restrict__ wfb,
                     ushort* __restrict__ wab, ushort* __restrict__ wbb) {
  const long i4 = (long)blockIdx.x * 256 + threadIdx.x;   // float4 index
  const float* src; ushort* dst; long j4; bool zero = false;
  if (i4 < NX4)                  { src = x;  dst = xb;  j4 = i4; zero = (i4 >= NXS4); }
  else if (i4 < NX4 + NF4)       { src = Wf; dst = wfb; j4 = i4 - NX4; }
  else if (i4 < NX4 + NF4 + NA4) { src = Wa; dst = wab; j4 = i4 - NX4 - NF4; }
  else                           { src = Wb; dst = wbb; j4 = i4 - NX4 - NF4 - NA4; }
  float4 v = {0.f, 0.f, 0.f, 0.f};
  if (!zero) v = *(const float4*)(src + j4 * 4);
  ushort4 o = { f2b(v.x), f2b(v.y), f2b(v.z), f2b(v.w) };
  *(ushort4*)(dst + j4 * 4) = o;
}

// ---------------- K1: h = relu(x @ Wf^T + bias) — best measured (87.5us) ------
__global__ __launch_bounds__(512)
void gemm_h_kernel(const ushort* __restrict__ A, const ushort* __restrict__ B,
                   const float* __restrict__ bias, ushort* __restrict__ H) {
  __shared__ ushort lds[3][24576];   // per buf: A[256][64] @0, B[128][64] @16384

  const int tid  = threadIdx.x;
  const int wid  = tid >> 6;           // 0..7
  const int lane = tid & 63;

  const int bid  = blockIdx.x;                       // 0..1175
  const int wgid = (bid & 7) * 147 + (bid >> 3);     // chunked XCD swizzle (1176%8==0)
  const int row0 = (wgid / 6) * 256;
  const int col0 = (wgid % 6) * 128;

  const int wrow = (wid >> 1) * 64;    // 0,64,128,192
  const int wcol = (wid & 1) * 64;     // 0,64

  const int srow = lane >> 3;                          // 0..7
  const int scol = ((lane & 7) ^ (lane >> 3)) * 8;     // pre-swizzled src col-chunk

  const ushort* Abase = A + (long)row0 * DIM;
  const ushort* Bbase = B + (long)col0 * DIM;

  auto STAGE_A = [&](int t, int buf) {   // 4 gload_lds per thread (32KB)
    const int k0 = t * 64;
#pragma unroll
    for (int i = 0; i < 4; ++i) {
      const int ch = i * 8 + wid;                      // 0..31 (8 rows each)
      gload_lds16(Abase + (long)(ch * 8 + srow) * DIM + k0 + scol,
                  &lds[buf][ch * 512]);
    }
  };
  auto STAGE_B = [&](int t, int buf) {   // 2 gload_lds per thread (16KB)
    const int k0 = t * 64;
#pragma unroll
    for (int i = 0; i < 2; ++i) {
      const int ch = i * 8 + wid;                      // 0..15
      gload_lds16(Bbase + (long)(ch * 8 + srow) * DIM + k0 + scol,
                  &lds[buf][16384 + ch * 512]);
    }
  };

  f32x4 acc[4][4] = {};

  STAGE_A(0, 0); STAGE_B(0, 0);
  STAGE_A(1, 1); STAGE_B(1, 1);
  asm volatile("s_waitcnt vmcnt(6)" ::: "memory");     // tile 0 landed; tile 1 in flight
  __builtin_amdgcn_s_barrier();

  int c = 0;
#pragma unroll 1
  for (int t = 0; t < 12; ++t) {
    const int nb = (c == 0) ? 2 : c - 1;               // (t+2)%3
    const ushort* Ab = &lds[c][0];
    const ushort* Bb = &lds[c][16384];

    // ================= phase 0 : kk=0 =================
    {
      const int j = lane >> 4;                         // k-chunk 0..3
      bf16x8 a[4], b[4];
#pragma unroll
      for (int m = 0; m < 4; ++m) {
        const int ra = wrow + m * 16 + (lane & 15);
        a[m] = *(const bf16x8*)(Ab + ra * 64 + ((j ^ (ra & 7)) << 3));
      }
#pragma unroll
      for (int n = 0; n < 4; ++n) {
        const int rb = wcol + n * 16 + (lane & 15);
        b[n] = *(const bf16x8*)(Bb + rb * 64 + ((j ^ (rb & 7)) << 3));
      }
      if (t < 10) STAGE_A(t + 2, nb);                  // prefetch half 1 of tile t+2
      __builtin_amdgcn_s_barrier();
      asm volatile("s_waitcnt lgkmcnt(0)" ::: "memory");
      __builtin_amdgcn_sched_barrier(0);
      __builtin_amdgcn_s_setprio(1);
#pragma unroll
      for (int n = 0; n < 4; ++n)
#pragma unroll
        for (int m = 0; m < 4; ++m)
          acc[m][n] = __builtin_amdgcn_mfma_f32_16x16x32_bf16(a[m], b[n], acc[m][n], 0, 0, 0);
      __builtin_amdgcn_s_setprio(0);
      __builtin_amdgcn_sched_barrier(0);
      __builtin_amdgcn_s_barrier();
    }
    // ================= phase 1 : kk=1 =================
    {
      const int j = 4 + (lane >> 4);                   // k-chunk 4..7
      bf16x8 a[4], b[4];
#pragma unroll
      for (int m = 0; m < 4; ++m) {
        const int ra = wrow + m * 16 + (lane & 15);
        a[m] = *(const bf16x8*)(Ab + ra * 64 + ((j ^ (ra & 7)) << 3));
      }
#pragma unroll
      for (int n = 0; n < 4; ++n) {
        const int rb = wcol + n * 16 + (lane & 15);
        b[n] = *(const bf16x8*)(Bb + rb * 64 + ((j ^ (rb & 7)) << 3));
      }
      if (t < 10) STAGE_B(t + 2, nb);                  // prefetch half 2 of tile t+2
      if (t < 10) {
        asm volatile("s_waitcnt vmcnt(6)" ::: "memory"); // t+1 landed; t+2 in flight
      } else if (t == 10) {
        asm volatile("s_waitcnt vmcnt(0)" ::: "memory"); // drain tile 11
      }
      __builtin_amdgcn_s_barrier();
      asm volatile("s_waitcnt lgkmcnt(0)" ::: "memory");
      __builtin_amdgcn_sched_barrier(0);
      __builtin_amdgcn_s_setprio(1);
#pragma unroll
      for (int n = 0; n < 4; ++n)
#pragma unroll
        for (int m = 0; m < 4; ++m)
          acc[m][n] = __builtin_amdgcn_mfma_f32_16x16x32_bf16(a[m], b[n], acc[m][n], 0, 0, 0);
      __builtin_amdgcn_s_setprio(0);
      __builtin_amdgcn_sched_barrier(0);
      __builtin_amdgcn_s_barrier();
    }
    c = (c == 2) ? 0 : c + 1;
  }

  const int lq = lane >> 4;
  const int lc = lane & 15;
#pragma unroll
  for (int n = 0; n < 4; ++n) {
    const int cg = col0 + wcol + n * 16 + lc;
    const float bv = bias[cg];
#pragma unroll
    for (int m = 0; m < 4; ++m) {
      const int rg = row0 + wrow + m * 16 + lq * 4;
#pragma unroll
      for (int r2 = 0; r2 < 4; ++r2) {
        float v = acc[m][n][r2] + bv;
        v = fmaxf(v, 0.0f);
        H[(long)(rg + r2) * DIM + cg] = f2b(v);
      }
    }
  }
}

// ---------------- K2: gate + block-local softmax stats -------------------------
__global__ __launch_bounds__(512)
void gate_stats_kernel(const ushort* __restrict__ Hm, const ushort* __restrict__ Wa,
                       const ushort* __restrict__ Wb, const float* __restrict__ Wc,
                       float* __restrict__ logits, float* __restrict__ part2) {
  __shared__ ushort Hs [128 * 64];
  __shared__ ushort Was[128 * 64];
  __shared__ ushort Wbs[128 * 64];
  __shared__ float  l_lds[128];
  __shared__ float  e_lds[128];
  __shared__ float  mb_lds;
  const int tid  = threadIdx.x;
  const int wid  = tid >> 6;           // 0..7
  const int lane = tid & 63;
  const int row0 = blockIdx.x * 128;

  f32x4 fa[8] = {};
  f32x4 fb[8] = {};

  const int ld_r = lane >> 3;
  const int ld_c = (lane & 7) * 8;

  for (int k0 = 0; k0 < DIM; k0 += 64) {
    __syncthreads();
#pragma unroll
    for (int i = 0; i < 2; ++i) {
      const int ch = i * 8 + wid;      // 0..15
      const int r  = ch * 8 + ld_r;    // 0..127
      gload_lds16(Hm + (long)(row0 + r) * DIM + k0 + ld_c, Hs  + ch * 512);
      gload_lds16(Wa + (long)r * DIM        + k0 + ld_c, Was + ch * 512);
      gload_lds16(Wb + (long)r * DIM        + k0 + ld_c, Wbs + ch * 512);
    }
    __syncthreads();
#pragma unroll
    for (int kk = 0; kk < 2; ++kk) {
      const int kc = kk * 32 + (lane >> 4) * 8;
      bf16x8 h = *(const bf16x8*)(Hs + (wid * 16 + (lane & 15)) * 64 + kc);
#pragma unroll
      for (int n = 0; n < 8; ++n) {
        bf16x8 wa = *(const bf16x8*)(Was + (n * 16 + (lane & 15)) * 64 + kc);
        bf16x8 wb = *(const bf16x8*)(Wbs + (n * 16 + (lane & 15)) * 64 + kc);
        fa[n] = __builtin_amdgcn_mfma_f32_16x16x32_bf16(h, wa, fa[n], 0, 0, 0);
        fb[n] = __builtin_amdgcn_mfma_f32_16x16x32_bf16(h, wb, fb[n], 0, 0, 0);
      }
    }
  }

  {
    const int lc = lane & 15;
    const int lq = lane >> 4;
    float g[4];
#pragma unroll
    for (int r = 0; r < 4; ++r) {
      float s = 0.f;
#pragma unroll
      for (int n = 0; n < 8; ++n) {
        float av = fmaxf(fa[n][r], 0.f);
        float sg = 1.f / (1.f + expf(-fb[n][r]));
        s += av * sg * Wc[n * 16 + lc];
      }
      s += __shfl_xor(s, 1);
      s += __shfl_xor(s, 2);
      s += __shfl_xor(s, 4);
      s += __shfl_xor(s, 8);
      g[r] = s;
    }
    if (lc == 0) {
      const int rb = wid * 16 + lq * 4;
#pragma unroll
      for (int r = 0; r < 4; ++r) {
        l_lds[rb + r] = g[r];
        const int nidx = row0 + rb + r;
        if (nidx < NPTS) logits[nidx] = g[r];
      }
    }
  }
  __syncthreads();

  // phase B: block stats (wave 0; fixed-order trees, deterministic)
  if (tid < 64) {
    float a0 = (row0 + tid      < NPTS) ? l_lds[tid]      : -1e30f;
    float a1 = (row0 + 64 + tid < NPTS) ? l_lds[64 + tid] : -1e30f;
    float m = fmaxf(a0, a1);
    for (int o = 32; o > 0; o >>= 1) m = fmaxf(m, __shfl_xor(m, o));
    if (tid == 0) mb_lds = m;
  }
  __syncthreads();
  const float mb = mb_lds;
  if (tid < 128) {
    const int n = row0 + tid;
    e_lds[tid] = (n < NPTS) ? expf(l_lds[tid] - mb) : 0.f;
  }
  __syncthreads();
  if (tid < 64) {
    float s = e_lds[tid] + e_lds[tid + 64];
    for (int o = 32; o > 0; o >>= 1) s += __shfl_xor(s, o);
    if (tid == 0) { part2[blockIdx.x * 2] = mb; part2[blockIdx.x * 2 + 1] = s; }
  }
}

// ---------------- K3: combine 392 block stats -> (M, denom) -------------------
__global__ __launch_bounds__(512)
void comb392_kernel(const float* __restrict__ part2, float* __restrict__ stats) {
  __shared__ float red[512];
  const int tid = threadIdx.x;
  const float m = (tid < NRB) ? part2[tid * 2] : -1e30f;
  red[tid] = m; __syncthreads();
  for (int s = 256; s > 0; s >>= 1) {
    if (tid < s) red[tid] = fmaxf(red[tid], red[tid + s]);
    __syncthreads();
  }
  const float M = red[0];
  __syncthreads();
  red[tid] = (tid < NRB) ? expf(m - M) * part2[tid * 2 + 1] : 0.f;
  __syncthreads();
  for (int s = 256; s > 0; s >>= 1) {
    if (tid < s) red[tid] += red[tid + s];
    __syncthreads();
  }
  if (tid == 0) { stats[0] = M; stats[1] = red[0]; }
}

// ---------------- K4: partial[b][d] = sum_{n in chunk} exp(l_n - M) * h[n][d] --
__global__ __launch_bounds__(192)
void weighted_partial_kernel(const ushort* __restrict__ Hm, const float* __restrict__ logits,
                             const float* __restrict__ stats, float* __restrict__ part) {
  __shared__ float w[128];
  const int b = blockIdx.x, tid = threadIdx.x;
  const int n0 = b * 128;
  if (tid < 128) {
    const int n = n0 + tid;
    w[tid] = (n < NPTS) ? expf(logits[n] - stats[0]) : 0.f;
  }
  __syncthreads();
  float4 acc = {0.f, 0.f, 0.f, 0.f};
  const ushort* hp = Hm + (long)n0 * DIM + tid * 4;
#pragma unroll 4
  for (int r = 0; r < 128; ++r) {
    const float wr = w[r];
    ushort4 v = *(const ushort4*)(hp + (long)r * DIM);
    acc.x += wr * b2f(v.x);
    acc.y += wr * b2f(v.y);
    acc.z += wr * b2f(v.z);
    acc.w += wr * b2f(v.w);
  }
  ((float4*)(part + (long)b * DIM))[tid] = acc;
}

// ---------------- K5: out[d] = (sum_b part[b][d]) / denom ----------------------
__global__ void final_reduce_kernel(const float* __restrict__ part,
                                    const float* __restrict__ stats,
                                    float* __restrict__ out) {
  const int c = blockIdx.x * blockDim.x + threadIdx.x;
  if (c >= DIM) return;
  float s = 0.f;
  for (int b = 0; b < NRB; ++b) s += part[(long)b * DIM + c];
  out[c] = s / stats[1];
}

extern "C" void kernel_launch(void* const* d_in, const int* in_sizes, int n_in,
                              void* d_out, int out_size, void* d_ws, size_t ws_size,
                              hipStream_t stream) {
  const float* x  = (const float*)d_in[0];
  const float* Wf = (const float*)d_in[1];
  const float* bf = (const float*)d_in[2];
  const float* Wa = (const float*)d_in[3];
  const float* Wb = (const float*)d_in[4];
  const float* Wc = (const float*)d_in[5];
  float* out = (float*)d_out;

  char* p = (char*)d_ws;
  ushort* xb  = (ushort*)p; p += (size_t)NPAD * DIM * 2;   // 77.1 MB
  ushort* hb  = (ushort*)p; p += (size_t)NPAD * DIM * 2;   // 77.1 MB
  ushort* wfb = (ushort*)p; p += (size_t)DIM * DIM * 2;
  ushort* wab = (ushort*)p; p += (size_t)DATT * DIM * 2;
  ushort* wbb = (ushort*)p; p += (size_t)DATT * DIM * 2;
  float* logits = (float*)p; p += (size_t)NPAD * 4;
  float* stats  = (float*)p; p += 256;
  float* part2  = (float*)p; p += (size_t)NRB * 2 * 4 + 256;
  float* part   = (float*)p; p += (size_t)NRB * DIM * 4;

  cvt_all4_kernel<<<38400, 256, 0, stream>>>(x, Wf, Wa, Wb, xb, wfb, wab, wbb);

  gemm_h_kernel<<<196 * 6, 512, 0, stream>>>(xb, wfb, bf, hb);
  gate_stats_kernel<<<NRB, 512, 0, stream>>>(hb, wab, wbb, Wc, logits, part2);
  comb392_kernel<<<1, 512, 0, stream>>>(part2, stats);
  weighted_partial_kernel<<<NRB, 192, 0, stream>>>(hb, logits, stats, part);
  final_reduce_kernel<<<3, 256, 0, stream>>>(part, stats, out);
}